// Round 24
// baseline (61.352 us; speedup 1.0000x reference)
//
#include <hip/hip_runtime.h>

typedef __attribute__((ext_vector_type(2))) float f32x2;

#define NS 1024      // N samples
#define MM 64        // M patches
#define CC 4         // C compartments
#define NSTEPS 100
#define CLIPMAX 1e10f

// Broadcast lane k's value to all lanes via v_readlane (setup only).
__device__ __forceinline__ float rdlane(float v, int k) {
    return __uint_as_float(__builtin_amdgcn_readlane(__float_as_uint(v), k));
}
// Force a (wave-uniform) value into an SGPR.
__device__ __forceinline__ float sfirst(float v) {
    return __uint_as_float(__builtin_amdgcn_readfirstlane(__float_as_uint(v)));
}

// r24 kernel 1: coalesced-read transpose of the Rt bijection into ws[n][j][i].
// Forward map (verified r1-r23): block n, lane i, index j reads
//   R[s][m][q], s=(i&15)*64+j, m=(n&15)*4+(i>>4), q=n>>4.
// Inverse: n=(q<<4)|(m>>2), i=((m&3)<<4)|(s>>6), j=s&63.
// Block s reads R[s] fully coalesced (q = flat&63 fastest); writes scattered
// (fire-and-forget; 16 different s-blocks fill each 64B destination line,
// merged in L2). This removes the 64-transactions-per-load gather that r24's
// re-fit identified as ~70% of the 55us kernel (r20/r21 scaling evidence).
extern "C" __global__ __launch_bounds__(256)
void transpose_kernel(const float* __restrict__ R, float* __restrict__ ws) {
    const int s = blockIdx.x;
    const int t = threadIdx.x;              // 0..255
    const float* Rs = R + (size_t)s * (MM * MM);
    const int j   = s & 63;
    const int shi = s >> 6;
    #pragma unroll
    for (int k = 0; k < 16; ++k) {
        const int flat = t + 256 * k;       // 0..4095
        const int m = flat >> 6;
        const int q = flat & 63;
        const float v = Rs[flat];           // coalesced read
        const int n = (q << 4) | (m >> 2);
        const int i = ((m & 3) << 4) | shi;
        ws[(size_t)n * (MM * MM) + j * MM + i] = v;   // scattered write
    }
}

// Main kernel = r23 (series phase-A with composed exp, LDS p-broadcast loop)
// with ONE change: the G power-sum gather reads ws[n][j][i] -- 64 perfectly
// coalesced 256B loads -- instead of 64 scattered-by-lane loads over R.
extern "C" __global__
__attribute__((amdgpu_flat_work_group_size(64, 64), amdgpu_waves_per_eu(1, 1)))
void metapop_kernel(
    const float* __restrict__ R,     // (NS, MM, MM)
    const float* __restrict__ T,     // (NS, CC, CC)
    const float* __restrict__ rho0,  // (NS, MM, CC)
    const float* __restrict__ beta,  // (NS,)
    const float* __restrict__ ws,    // (NS, MM, MM) transposed Rt [n][j][i]
    float* __restrict__ out)         // (NSTEPS, NS, MM, CC)
{
    const int n    = blockIdx.x;
    const int lane = threadIdx.x;    // 0..63

    __shared__ float pbuf[MM];

    const float* Rn = R + (size_t)n * (MM * MM);

    // ---- Rrow pairs: Rrow2[k2] = (R[n,lane,2k2], R[n,lane,2k2+1]) ----
    f32x2 Rrow2[32];
    {
        const float4* p4 = (const float4*)(Rn + lane * MM);
        #pragma unroll
        for (int q = 0; q < 16; ++q) {
            float4 v = p4[q];
            Rrow2[2*q]   = (f32x2){v.x, v.y};
            Rrow2[2*q+1] = (f32x2){v.z, v.w};
        }
    }

    // ---- ntot[lane] = sum_i R[n,i,lane] (L1-hot after Rrow) ----
    float nt = 0.f;
    #pragma unroll
    for (int i = 0; i < MM; ++i) nt += Rn[i * MM + lane];
    const float binv = beta[n] / nt;

    // ---- G power sums from ws (coalesced: lane reads ws[n][j][lane]) ----
    float S1 = 0.f, S2 = 0.f, S3 = 0.f, S4 = 0.f;
    {
        const float* wsn = ws + (size_t)n * (MM * MM);
        #pragma unroll
        for (int j = 0; j < MM; ++j) {
            float g  = wsn[j * MM + lane] * rdlane(binv, j);
            float g2 = g * g;
            S1 += g;  S2 += g2;  S3 += g2 * g;  S4 += g2 * g2;
        }
    }
    // log-series coeffs composed with 1-exp(-u), truncated at r^4
    const float c1 = S1, c2 = 0.5f * S2, c3 = (1.f / 3.f) * S3, c4 = 0.25f * S4;
    const float c1sq = c1 * c1;
    const float d1 = c1;
    const float d2 = c2 - 0.5f * c1sq;
    const float d3 = c3 - c1 * c2 + (1.f / 6.f) * c1sq * c1;
    const float d4 = c4 - c1 * c3 - 0.5f * c2 * c2 + 0.5f * c1sq * c2
                   - (1.f / 24.f) * c1sq * c1sq;

    // ---- keep Rrow resident ----
    #pragma unroll
    for (int q = 0; q < 32; ++q) asm volatile("" : "+v"(Rrow2[q]));

    // ---- T[n] -> SGPRs ----
    float tt[CC][CC];
    {
        const float* Tn = T + n * (CC * CC);
        #pragma unroll
        for (int k = 0; k < CC; ++k)
            #pragma unroll
            for (int l = 0; l < CC; ++l)
                tt[k][l] = sfirst(Tn[k * CC + l]);
    }

    // ---- rho0 ----
    float rh[CC];
    {
        float4 v = *(const float4*)(rho0 + (size_t)n * (MM * CC) + lane * CC);
        rh[0] = v.x; rh[1] = v.y; rh[2] = v.z; rh[3] = v.w;
    }

    float* ob = out + (size_t)n * (MM * CC) + lane * CC;
    const size_t stride = (size_t)NS * MM * CC;

    for (int step = 0; step < NSTEPS; ++step) {
        // trajectory records PRE-update state; coalesced float4, fire-and-forget
        *(float4*)(ob + (size_t)step * stride) =
            make_float4(rh[0], rh[1], rh[2], rh[3]);

        // phase A: p = r*(d1 + r*(d2 + r*(d3 + r*d4)))  [no exp]
        const float r1 = rh[1];
        const float p  = r1 * (d1 + r1 * (d2 + r1 * (d3 + r1 * d4)));

        // p-broadcast via LDS, NO barrier (single wave: lgkmcnt orders DS ops)
        pbuf[lane] = p;

        // phase B: s = sum_k Rrow[k]*p[k]; 16x uniform-addr ds_read_b128
        f32x2 a0 = {0.f, 0.f}, a1 = {0.f, 0.f}, a2 = {0.f, 0.f}, a3 = {0.f, 0.f};
        {
            const float4* pb4 = (const float4*)pbuf;
            #pragma unroll
            for (int q = 0; q < 4; ++q) {
                float4 pv;
                pv = pb4[q];
                a0 += Rrow2[2*q]      * (f32x2){pv.x, pv.y};
                a0 += Rrow2[2*q + 1]  * (f32x2){pv.z, pv.w};
                pv = pb4[q + 4];
                a1 += Rrow2[2*q + 8]  * (f32x2){pv.x, pv.y};
                a1 += Rrow2[2*q + 9]  * (f32x2){pv.z, pv.w};
                pv = pb4[q + 8];
                a2 += Rrow2[2*q + 16] * (f32x2){pv.x, pv.y};
                a2 += Rrow2[2*q + 17] * (f32x2){pv.z, pv.w};
                pv = pb4[q + 12];
                a3 += Rrow2[2*q + 24] * (f32x2){pv.x, pv.y};
                a3 += Rrow2[2*q + 25] * (f32x2){pv.z, pv.w};
            }
        }
        const f32x2 aa = (a0 + a1) + (a2 + a3);
        const float ssum = aa.x + aa.y;
        const float sr   = (rh[0] + rh[1]) + (rh[2] + rh[3]);
        const float ninf = (1.f - sr) * ssum;

        // phase C (lane-local)
        float nr[CC];
        #pragma unroll
        for (int l = 0; l < CC; ++l) {
            float v = rh[0] * tt[0][l] + rh[1] * tt[1][l]
                    + rh[2] * tt[2][l] + rh[3] * tt[3][l];
            if (l == 0) v += ninf;
            nr[l] = fminf(fmaxf(v, 0.f), CLIPMAX);
        }
        #pragma unroll
        for (int l = 0; l < CC; ++l) rh[l] = nr[l];
    }
}

extern "C" void kernel_launch(void* const* d_in, const int* in_sizes, int n_in,
                              void* d_out, int out_size, void* d_ws, size_t ws_size,
                              hipStream_t stream) {
    const float* R    = (const float*)d_in[0];
    const float* T    = (const float*)d_in[1];
    const float* rho0 = (const float*)d_in[2];
    const float* beta = (const float*)d_in[3];
    float* out = (float*)d_out;
    float* ws  = (float*)d_ws;   // needs NS*MM*MM*4 = 16.8 MB

    hipLaunchKernelGGL(transpose_kernel, dim3(NS), dim3(256), 0, stream, R, ws);
    hipLaunchKernelGGL(metapop_kernel, dim3(NS), dim3(64), 0, stream,
                       R, T, rho0, beta, ws, out);
}